// Round 3
// baseline (1972.292 us; speedup 1.0000x reference)
//
#include <hip/hip_runtime.h>
#include <hip/hip_bf16.h>
#include <math.h>

#define V 32000
#define T 128
#define B 64
#define E 32
#define H 8
#define TB (T*B)   // 8192

#define R3 16      // rows per block (k_partial / k_write)
#define NT3 320    // threads (5 waves); 320*4 = 1280 cols per chunk
#define NW3 5
#define VS 5       // V splits; per split: 6400 cols = 5 chunks of 1280
#define CPS 5      // chunks per split

typedef float f32x4 __attribute__((ext_vector_type(4)));

// ---------------- params struct ----------------
struct P1 {
  const int* x; const float* emb;
  const float* Wf1; const float* bf1; const float* Wi1; const float* bi1;
  const float* WC1; const float* bC1; const float* Wo1; const float* bo1;
  const float* Wf2; const float* bf2; const float* Wi2; const float* bi2;
  const float* WC2; const float* bC2; const float* Wo2; const float* bo2;
};

__device__ __forceinline__ float sigm_f(float x) { return 1.f / (1.f + __expf(-x)); }
__device__ __forceinline__ float tanh_f(float x) { float e = __expf(2.f * x); return 1.f - 2.f / (e + 1.f); }

// ---------------- kernel 1: embed + e-part projections (bias folded in) ----------------
// pe layout: pe[(d*11 + g)*TB + r], g: 0=f,1=i,2=o,3..10=C[j];  r = t*B+b
__global__ __launch_bounds__(256) void k_embed(P1 p, float* __restrict__ pe) {
  int r = blockIdx.x * 256 + threadIdx.x;
  int idx = p.x[r];
  const float* e = p.emb + (long)idx * E;
  float ev[E];
  #pragma unroll
  for (int k = 0; k < E; k += 4) {
    float4 v4 = *(const float4*)(e + k);
    ev[k] = v4.x; ev[k+1] = v4.y; ev[k+2] = v4.z; ev[k+3] = v4.w;
  }
  #pragma unroll
  for (int d = 0; d < 2; ++d) {
    const float* Wf = d ? p.Wf2 : p.Wf1;
    const float* Wi = d ? p.Wi2 : p.Wi1;
    const float* Wo = d ? p.Wo2 : p.Wo1;
    const float* WC = d ? p.WC2 : p.WC1;
    const float* bC = d ? p.bC2 : p.bC1;
    float af = (d ? p.bf2 : p.bf1)[0];
    float ai = (d ? p.bi2 : p.bi1)[0];
    float ao = (d ? p.bo2 : p.bo1)[0];
    float ac[H];
    #pragma unroll
    for (int j = 0; j < H; ++j) ac[j] = bC[j];
    #pragma unroll
    for (int k = 0; k < E; ++k) {
      float ek = ev[k];
      af += ek * Wf[8 + k];
      ai += ek * Wi[8 + k];
      ao += ek * Wo[8 + k];
      #pragma unroll
      for (int j = 0; j < H; ++j) ac[j] += ek * WC[(8 + k) * H + j];
    }
    float* ped = pe + d * 11 * TB;
    ped[0 * TB + r] = af;
    ped[1 * TB + r] = ai;
    ped[2 * TB + r] = ao;
    #pragma unroll
    for (int j = 0; j < H; ++j) ped[(3 + j) * TB + r] = ac[j];
  }
}

// ---------------- kernel 2: sequential LSTM (one block per direction) ----------------
// hcat layout: hcat[r*16 + dir*8 + j]   (total_h, pre-update h recorded)
__global__ __launch_bounds__(64) void k_lstm(P1 p, const float* __restrict__ pe, float* __restrict__ hcat) {
  int dir = blockIdx.x;
  int lane = threadIdx.x;
  const float* Wf = dir ? p.Wf2 : p.Wf1;
  const float* Wi = dir ? p.Wi2 : p.Wi1;
  const float* Wo = dir ? p.Wo2 : p.Wo1;
  const float* WC = dir ? p.WC2 : p.WC1;
  float wf[8], wi[8], wo[8], wc[8][8];
  #pragma unroll
  for (int k = 0; k < 8; ++k) { wf[k] = Wf[k]; wi[k] = Wi[k]; wo[k] = Wo[k]; }
  #pragma unroll
  for (int k = 0; k < 8; ++k)
    #pragma unroll
    for (int j = 0; j < 8; ++j) wc[k][j] = WC[k * H + j];

  float h[8], C[8];
  #pragma unroll
  for (int j = 0; j < 8; ++j) { h[j] = 0.f; C[j] = 0.f; }

  const float* ped = pe + dir * 11 * TB;

  // software-pipelined pe reads: prefetch step s+1 while computing step s
  int tf = dir ? (T - 1) : 0;
  int rf = tf * B + lane;
  float nf = ped[0 * TB + rf], ni = ped[1 * TB + rf], no_ = ped[2 * TB + rf];
  float nc[8];
  #pragma unroll
  for (int j = 0; j < 8; ++j) nc[j] = ped[(3 + j) * TB + rf];

  for (int s = 0; s < T; ++s) {
    int t = dir ? (T - 1 - s) : s;
    int r = t * B + lane;
    float af = nf, ai = ni, ao = no_;
    float ac[8];
    #pragma unroll
    for (int j = 0; j < 8; ++j) ac[j] = nc[j];

    if (s + 1 < T) {
      int t2 = dir ? (T - 2 - s) : (s + 1);
      int r2 = t2 * B + lane;
      nf = ped[0 * TB + r2]; ni = ped[1 * TB + r2]; no_ = ped[2 * TB + r2];
      #pragma unroll
      for (int j = 0; j < 8; ++j) nc[j] = ped[(3 + j) * TB + r2];
    }

    // record pre-update h (scan outputs carry-in h)
    float* hc = hcat + r * 16 + dir * 8;
    #pragma unroll
    for (int j = 0; j < 8; ++j) hc[j] = h[j];

    #pragma unroll
    for (int k = 0; k < 8; ++k) {
      float hk = h[k];
      af += hk * wf[k];
      ai += hk * wi[k];
      ao += hk * wo[k];
      #pragma unroll
      for (int j = 0; j < 8; ++j) ac[j] += hk * wc[k][j];
    }
    float f = sigm_f(af), i = sigm_f(ai), o = sigm_f(ao);
    #pragma unroll
    for (int j = 0; j < 8; ++j) {
      float Cn = f * C[j] + i + tanh_f(ac[j]);
      C[j] = Cn;
      h[j] = o * tanh_f(Cn);
    }
  }
}

// ---------------- kernel 3a: partial sum-exp per (row-tile, v-split) ----------------
// |logit| <= 16*max|Wout| + |bout| ~ 8  =>  exp(l) safe in fp32 without max-sub.
__global__ __launch_bounds__(NT3) void k_partial(const float* __restrict__ hcat,
                                                 const float* __restrict__ Wout,
                                                 const float* __restrict__ bout,
                                                 float* __restrict__ pms) {
  __shared__ float sTH[R3 * 16];
  __shared__ float sWS[NW3][R3];
  int tid = threadIdx.x;
  int r0 = blockIdx.x * R3;
  int v0 = blockIdx.y * (CPS * NT3 * 4);
  if (tid < R3 * 16) sTH[tid] = hcat[r0 * 16 + tid];
  __syncthreads();

  float sum[R3];
  #pragma unroll
  for (int q = 0; q < R3; ++q) sum[q] = 0.f;

  for (int c = 0; c < CPS; ++c) {
    int v = v0 + c * (NT3 * 4) + tid * 4;
    float4 w[16];
    #pragma unroll
    for (int k = 0; k < 16; ++k) w[k] = *(const float4*)(Wout + k * V + v);
    float4 bb = *(const float4*)(bout + v);
    #pragma unroll
    for (int q = 0; q < R3; ++q) {
      const float4* th4 = (const float4*)(sTH + q * 16);
      float4 t0 = th4[0], t1 = th4[1], t2 = th4[2], t3 = th4[3];
      float th[16] = {t0.x,t0.y,t0.z,t0.w, t1.x,t1.y,t1.z,t1.w,
                      t2.x,t2.y,t2.z,t2.w, t3.x,t3.y,t3.z,t3.w};
      float lx = bb.x, ly = bb.y, lz = bb.z, lw = bb.w;
      #pragma unroll
      for (int k = 0; k < 16; ++k) {
        lx += th[k] * w[k].x; ly += th[k] * w[k].y;
        lz += th[k] * w[k].z; lw += th[k] * w[k].w;
      }
      sum[q] += __expf(lx) + __expf(ly) + __expf(lz) + __expf(lw);
    }
  }

  int wave = tid >> 6, lane = tid & 63;
  #pragma unroll
  for (int q = 0; q < R3; ++q) {
    float sq = sum[q];
    #pragma unroll
    for (int off = 32; off >= 1; off >>= 1) sq += __shfl_xor(sq, off);
    if (lane == 0) sWS[wave][q] = sq;
  }
  __syncthreads();
  if (tid < R3) {
    float s = 0.f;
    #pragma unroll
    for (int wv = 0; wv < NW3; ++wv) s += sWS[wv][tid];
    pms[(long)(r0 + tid) * VS + blockIdx.y] = s;
  }
}

// ---------------- kernel 3b: Z = log(sum of partials) ----------------
__global__ __launch_bounds__(256) void k_reduce(const float* __restrict__ pms, float* __restrict__ Z) {
  int r = blockIdx.x * 256 + threadIdx.x;
  float s = 0.f;
  #pragma unroll
  for (int i = 0; i < VS; ++i) s += pms[(long)r * VS + i];
  Z[r] = logf(s);
}

// ---------------- kernel 3c: recompute logits, write out (non-temporal) ----------------
__global__ __launch_bounds__(NT3) void k_write(const float* __restrict__ hcat,
                                               const float* __restrict__ Wout,
                                               const float* __restrict__ bout,
                                               const float* __restrict__ Z,
                                               float* __restrict__ out) {
  __shared__ float sTH[R3 * 16];
  __shared__ float sZ[R3];
  int tid = threadIdx.x;
  int r0 = blockIdx.x * R3;
  int v0 = blockIdx.y * (CPS * NT3 * 4);
  if (tid < R3 * 16) sTH[tid] = hcat[r0 * 16 + tid];
  if (tid < R3) sZ[tid] = Z[r0 + tid];
  __syncthreads();

  for (int c = 0; c < CPS; ++c) {
    int v = v0 + c * (NT3 * 4) + tid * 4;
    float4 w[16];
    #pragma unroll
    for (int k = 0; k < 16; ++k) w[k] = *(const float4*)(Wout + k * V + v);
    float4 bb = *(const float4*)(bout + v);
    #pragma unroll
    for (int q = 0; q < R3; ++q) {
      const float4* th4 = (const float4*)(sTH + q * 16);
      float4 t0 = th4[0], t1 = th4[1], t2 = th4[2], t3 = th4[3];
      float th[16] = {t0.x,t0.y,t0.z,t0.w, t1.x,t1.y,t1.z,t1.w,
                      t2.x,t2.y,t2.z,t2.w, t3.x,t3.y,t3.z,t3.w};
      float lx = bb.x, ly = bb.y, lz = bb.z, lw = bb.w;
      #pragma unroll
      for (int k = 0; k < 16; ++k) {
        lx += th[k] * w[k].x; ly += th[k] * w[k].y;
        lz += th[k] * w[k].z; lw += th[k] * w[k].w;
      }
      float Zq = sZ[q];
      f32x4 o4;
      o4.x = lx - Zq; o4.y = ly - Zq; o4.z = lz - Zq; o4.w = lw - Zq;
      __builtin_nontemporal_store(o4, (f32x4*)(out + (long)(r0 + q) * V + v));
    }
  }
}

extern "C" void kernel_launch(void* const* d_in, const int* in_sizes, int n_in,
                              void* d_out, int out_size, void* d_ws, size_t ws_size,
                              hipStream_t stream) {
  (void)in_sizes; (void)n_in; (void)out_size; (void)ws_size;
  P1 p;
  p.x   = (const int*)  d_in[0];
  p.emb = (const float*)d_in[1];
  p.Wf1 = (const float*)d_in[2];  p.bf1 = (const float*)d_in[3];
  p.Wi1 = (const float*)d_in[4];  p.bi1 = (const float*)d_in[5];
  p.WC1 = (const float*)d_in[6];  p.bC1 = (const float*)d_in[7];
  p.Wo1 = (const float*)d_in[8];  p.bo1 = (const float*)d_in[9];
  p.Wf2 = (const float*)d_in[10]; p.bf2 = (const float*)d_in[11];
  p.Wi2 = (const float*)d_in[12]; p.bi2 = (const float*)d_in[13];
  p.WC2 = (const float*)d_in[14]; p.bC2 = (const float*)d_in[15];
  p.Wo2 = (const float*)d_in[16]; p.bo2 = (const float*)d_in[17];
  const float* Wout = (const float*)d_in[18];
  const float* bout = (const float*)d_in[19];

  float* pe   = (float*)d_ws;            // 2*11*TB floats = 180224
  float* hcat = pe + 2 * 11 * TB;        // TB*16 floats   = 131072
  float* pms  = hcat + TB * 16;          // TB*VS floats   = 40960
  float* Zr   = pms + TB * VS;           // TB floats      = 8192
  float* out  = (float*)d_out;

  k_embed  <<<dim3(TB / 256),     dim3(256), 0, stream>>>(p, pe);
  k_lstm   <<<dim3(2),            dim3(64),  0, stream>>>(p, pe, hcat);
  k_partial<<<dim3(TB / R3, VS),  dim3(NT3), 0, stream>>>(hcat, Wout, bout, pms);
  k_reduce <<<dim3(TB / 256),     dim3(256), 0, stream>>>(pms, Zr);
  k_write  <<<dim3(TB / R3, VS),  dim3(NT3), 0, stream>>>(hcat, Wout, bout, Zr, out);
}

// Round 4
// 616.386 us; speedup vs baseline: 3.1998x; 3.1998x over previous
//
#include <hip/hip_runtime.h>
#include <hip/hip_bf16.h>
#include <math.h>

#define V 32000
#define T 128
#define B 64
#define E 32
#define H 8
#define TB (T*B)   // 8192

#define NT 320     // 5 waves; 4 cols/thread -> 1280 cols per block-chunk
#define NCH 25     // 32000 / 1280 v-chunks
#define G1 32      // row-groups pass 1 (256 rows/block)
#define G2 64      // row-groups pass 2 (128 rows/block)

// ---------------- params struct ----------------
struct P1 {
  const int* x; const float* emb;
  const float* Wf1; const float* bf1; const float* Wi1; const float* bi1;
  const float* WC1; const float* bC1; const float* Wo1; const float* bo1;
  const float* Wf2; const float* bf2; const float* Wi2; const float* bi2;
  const float* WC2; const float* bC2; const float* Wo2; const float* bo2;
};

__device__ __forceinline__ float sigm_f(float x) { return 1.f / (1.f + __expf(-x)); }
__device__ __forceinline__ float tanh_f(float x) { float e = __expf(2.f * x); return 1.f - 2.f / (e + 1.f); }

// ---------------- kernel 1: embed + e-part projections (bias folded in) ----------------
__global__ __launch_bounds__(256) void k_embed(P1 p, float* __restrict__ pe) {
  int r = blockIdx.x * 256 + threadIdx.x;
  int idx = p.x[r];
  const float* e = p.emb + (long)idx * E;
  float ev[E];
  #pragma unroll
  for (int k = 0; k < E; k += 4) {
    float4 v4 = *(const float4*)(e + k);
    ev[k] = v4.x; ev[k+1] = v4.y; ev[k+2] = v4.z; ev[k+3] = v4.w;
  }
  #pragma unroll
  for (int d = 0; d < 2; ++d) {
    const float* Wf = d ? p.Wf2 : p.Wf1;
    const float* Wi = d ? p.Wi2 : p.Wi1;
    const float* Wo = d ? p.Wo2 : p.Wo1;
    const float* WC = d ? p.WC2 : p.WC1;
    const float* bC = d ? p.bC2 : p.bC1;
    float af = (d ? p.bf2 : p.bf1)[0];
    float ai = (d ? p.bi2 : p.bi1)[0];
    float ao = (d ? p.bo2 : p.bo1)[0];
    float ac[H];
    #pragma unroll
    for (int j = 0; j < H; ++j) ac[j] = bC[j];
    #pragma unroll
    for (int k = 0; k < E; ++k) {
      float ek = ev[k];
      af += ek * Wf[8 + k];
      ai += ek * Wi[8 + k];
      ao += ek * Wo[8 + k];
      #pragma unroll
      for (int j = 0; j < H; ++j) ac[j] += ek * WC[(8 + k) * H + j];
    }
    float* ped = pe + d * 11 * TB;
    ped[0 * TB + r] = af;
    ped[1 * TB + r] = ai;
    ped[2 * TB + r] = ao;
    #pragma unroll
    for (int j = 0; j < H; ++j) ped[(3 + j) * TB + r] = ac[j];
  }
}

// ---------------- kernel 2: sequential LSTM (one block per direction) ----------------
__global__ __launch_bounds__(64) void k_lstm(P1 p, const float* __restrict__ pe, float* __restrict__ hcat) {
  int dir = blockIdx.x;
  int lane = threadIdx.x;
  const float* Wf = dir ? p.Wf2 : p.Wf1;
  const float* Wi = dir ? p.Wi2 : p.Wi1;
  const float* Wo = dir ? p.Wo2 : p.Wo1;
  const float* WC = dir ? p.WC2 : p.WC1;
  float wf[8], wi[8], wo[8], wc[8][8];
  #pragma unroll
  for (int k = 0; k < 8; ++k) { wf[k] = Wf[k]; wi[k] = Wi[k]; wo[k] = Wo[k]; }
  #pragma unroll
  for (int k = 0; k < 8; ++k)
    #pragma unroll
    for (int j = 0; j < 8; ++j) wc[k][j] = WC[k * H + j];

  float h[8], C[8];
  #pragma unroll
  for (int j = 0; j < 8; ++j) { h[j] = 0.f; C[j] = 0.f; }

  const float* ped = pe + dir * 11 * TB;

  int tf = dir ? (T - 1) : 0;
  int rf = tf * B + lane;
  float nf = ped[0 * TB + rf], ni = ped[1 * TB + rf], no_ = ped[2 * TB + rf];
  float nc[8];
  #pragma unroll
  for (int j = 0; j < 8; ++j) nc[j] = ped[(3 + j) * TB + rf];

  for (int s = 0; s < T; ++s) {
    int t = dir ? (T - 1 - s) : s;
    int r = t * B + lane;
    float af = nf, ai = ni, ao = no_;
    float ac[8];
    #pragma unroll
    for (int j = 0; j < 8; ++j) ac[j] = nc[j];

    if (s + 1 < T) {
      int t2 = dir ? (T - 2 - s) : (s + 1);
      int r2 = t2 * B + lane;
      nf = ped[0 * TB + r2]; ni = ped[1 * TB + r2]; no_ = ped[2 * TB + r2];
      #pragma unroll
      for (int j = 0; j < 8; ++j) nc[j] = ped[(3 + j) * TB + r2];
    }

    float* hc = hcat + r * 16 + dir * 8;
    #pragma unroll
    for (int j = 0; j < 8; ++j) hc[j] = h[j];

    #pragma unroll
    for (int k = 0; k < 8; ++k) {
      float hk = h[k];
      af += hk * wf[k];
      ai += hk * wi[k];
      ao += hk * wo[k];
      #pragma unroll
      for (int j = 0; j < 8; ++j) ac[j] += hk * wc[k][j];
    }
    float f = sigm_f(af), i = sigm_f(ai), o = sigm_f(ao);
    #pragma unroll
    for (int j = 0; j < 8; ++j) {
      float Cn = f * C[j] + i + tanh_f(ac[j]);
      C[j] = Cn;
      h[j] = o * tanh_f(Cn);
    }
  }
}

// ---------------- pass 1: partial sum-exp; Wout slice held in registers ----------------
// grid (NCH, G1); block owns cols [chunk*1280, +1280) x rows [rg*256, +256)
// pms[row*NCH + chunk] = sum_{cols in chunk} exp(logit)
__global__ __launch_bounds__(NT) void k_part(const float* __restrict__ hcat,
                                             const float* __restrict__ Wout,
                                             const float* __restrict__ bout,
                                             float* __restrict__ pms) {
  __shared__ float sTH[16 * 16];
  __shared__ float sP[16][5];
  const int RPB = TB / G1;                 // 256
  int tid = threadIdx.x;
  int wave = tid >> 6, lane = tid & 63;
  int chunk = blockIdx.x;
  int row0 = blockIdx.y * RPB;
  int col4 = chunk * (NT * 4) + tid * 4;

  float4 w[16];
  #pragma unroll
  for (int k = 0; k < 16; ++k) w[k] = *(const float4*)(Wout + k * V + col4);
  float4 bb = *(const float4*)(bout + col4);

  for (int rt = 0; rt < RPB / 16; ++rt) {
    int r0 = row0 + rt * 16;
    __syncthreads();
    if (tid < 256) sTH[tid] = hcat[r0 * 16 + tid];
    __syncthreads();
    #pragma unroll
    for (int q = 0; q < 16; ++q) {
      const float4* th4 = (const float4*)(sTH + q * 16);
      float4 t0 = th4[0], t1 = th4[1], t2 = th4[2], t3 = th4[3];
      float th[16] = {t0.x,t0.y,t0.z,t0.w, t1.x,t1.y,t1.z,t1.w,
                      t2.x,t2.y,t2.z,t2.w, t3.x,t3.y,t3.z,t3.w};
      float lx = bb.x, ly = bb.y, lz = bb.z, lw = bb.w;
      #pragma unroll
      for (int k = 0; k < 16; ++k) {
        lx += th[k] * w[k].x; ly += th[k] * w[k].y;
        lz += th[k] * w[k].z; lw += th[k] * w[k].w;
      }
      float s = __expf(lx) + __expf(ly) + __expf(lz) + __expf(lw);
      #pragma unroll
      for (int off = 32; off >= 1; off >>= 1) s += __shfl_xor(s, off);
      if (lane == 0) sP[q][wave] = s;
    }
    __syncthreads();
    if (tid < 16) {
      float s = sP[tid][0] + sP[tid][1] + sP[tid][2] + sP[tid][3] + sP[tid][4];
      pms[(long)(r0 + tid) * NCH + chunk] = s;
    }
  }
}

// ---------------- Z = log(sum of partials) ----------------
__global__ __launch_bounds__(256) void k_reduce(const float* __restrict__ pms, float* __restrict__ Z) {
  int r = blockIdx.x * 256 + threadIdx.x;
  float s = 0.f;
  #pragma unroll
  for (int i = 0; i < NCH; ++i) s += pms[(long)r * NCH + i];
  Z[r] = logf(s);
}

// ---------------- pass 2: recompute logits, subtract Z, write ----------------
// grid (NCH, G2)
__global__ __launch_bounds__(NT) void k_wr(const float* __restrict__ hcat,
                                           const float* __restrict__ Wout,
                                           const float* __restrict__ bout,
                                           const float* __restrict__ Z,
                                           float* __restrict__ out) {
  __shared__ float sTH[16 * 16];
  __shared__ float sZ[16];
  const int RPB = TB / G2;                 // 128
  int tid = threadIdx.x;
  int chunk = blockIdx.x;
  int row0 = blockIdx.y * RPB;
  int col4 = chunk * (NT * 4) + tid * 4;

  float4 w[16];
  #pragma unroll
  for (int k = 0; k < 16; ++k) w[k] = *(const float4*)(Wout + k * V + col4);
  float4 bb = *(const float4*)(bout + col4);

  for (int rt = 0; rt < RPB / 16; ++rt) {
    int r0 = row0 + rt * 16;
    __syncthreads();
    if (tid < 256) sTH[tid] = hcat[r0 * 16 + tid];
    else if (tid < 256 + 16) sZ[tid - 256] = Z[r0 + tid - 256];
    __syncthreads();
    #pragma unroll
    for (int q = 0; q < 16; ++q) {
      const float4* th4 = (const float4*)(sTH + q * 16);
      float4 t0 = th4[0], t1 = th4[1], t2 = th4[2], t3 = th4[3];
      float th[16] = {t0.x,t0.y,t0.z,t0.w, t1.x,t1.y,t1.z,t1.w,
                      t2.x,t2.y,t2.z,t2.w, t3.x,t3.y,t3.z,t3.w};
      float lx = bb.x, ly = bb.y, lz = bb.z, lw = bb.w;
      #pragma unroll
      for (int k = 0; k < 16; ++k) {
        lx += th[k] * w[k].x; ly += th[k] * w[k].y;
        lz += th[k] * w[k].z; lw += th[k] * w[k].w;
      }
      float Zq = sZ[q];
      float4 o4;
      o4.x = lx - Zq; o4.y = ly - Zq; o4.z = lz - Zq; o4.w = lw - Zq;
      *(float4*)(out + (long)(r0 + q) * V + col4) = o4;
    }
  }
}

extern "C" void kernel_launch(void* const* d_in, const int* in_sizes, int n_in,
                              void* d_out, int out_size, void* d_ws, size_t ws_size,
                              hipStream_t stream) {
  (void)in_sizes; (void)n_in; (void)out_size; (void)ws_size;
  P1 p;
  p.x   = (const int*)  d_in[0];
  p.emb = (const float*)d_in[1];
  p.Wf1 = (const float*)d_in[2];  p.bf1 = (const float*)d_in[3];
  p.Wi1 = (const float*)d_in[4];  p.bi1 = (const float*)d_in[5];
  p.WC1 = (const float*)d_in[6];  p.bC1 = (const float*)d_in[7];
  p.Wo1 = (const float*)d_in[8];  p.bo1 = (const float*)d_in[9];
  p.Wf2 = (const float*)d_in[10]; p.bf2 = (const float*)d_in[11];
  p.Wi2 = (const float*)d_in[12]; p.bi2 = (const float*)d_in[13];
  p.WC2 = (const float*)d_in[14]; p.bC2 = (const float*)d_in[15];
  p.Wo2 = (const float*)d_in[16]; p.bo2 = (const float*)d_in[17];
  const float* Wout = (const float*)d_in[18];
  const float* bout = (const float*)d_in[19];

  float* pe   = (float*)d_ws;            // 2*11*TB          = 180224 f
  float* hcat = pe + 2 * 11 * TB;        // TB*16            = 131072 f
  float* pms  = hcat + TB * 16;          // TB*NCH           = 204800 f
  float* Zr   = pms + TB * NCH;          // TB               =   8192 f
  float* out  = (float*)d_out;           // total ws ~ 2.1 MB

  k_embed <<<dim3(TB / 256),  dim3(256), 0, stream>>>(p, pe);
  k_lstm  <<<dim3(2),         dim3(64),  0, stream>>>(p, pe, hcat);
  k_part  <<<dim3(NCH, G1),   dim3(NT),  0, stream>>>(hcat, Wout, bout, pms);
  k_reduce<<<dim3(TB / 256),  dim3(256), 0, stream>>>(pms, Zr);
  k_wr    <<<dim3(NCH, G2),   dim3(NT),  0, stream>>>(hcat, Wout, bout, Zr, out);
}